// Round 1
// baseline (215.171 us; speedup 1.0000x reference)
//
#include <hip/hip_runtime.h>
#include <hip/hip_bf16.h>
#include <stdint.h>

typedef unsigned short u16;

#define IN_F  4096
#define OUT_F 4096
#define BATCH 4096

// ---------- bf16 helpers ----------
__device__ __forceinline__ u16 f2bf(float f) {
    uint32_t u = __float_as_uint(f);
    uint32_t r = u + 0x7FFFu + ((u >> 16) & 1u);   // round-to-nearest-even
    return (u16)(r >> 16);
}

// ---------- prep kernels ----------
__global__ void zero_w_kernel(u16* __restrict__ Wb) {
    size_t tid = (size_t)blockIdx.x * blockDim.x + threadIdx.x;
    uint4 z = {0u, 0u, 0u, 0u};
    *(uint4*)(Wb + tid * 8) = z;                    // 8 bf16 zeros / thread
}

__global__ void convert_x_kernel(const float* __restrict__ X, u16* __restrict__ Xb) {
    size_t tid = (size_t)blockIdx.x * blockDim.x + threadIdx.x;
    const float4* p = (const float4*)(X + tid * 8);
    float4 a = p[0];
    float4 b = p[1];
    uint4 o;
    o.x = (uint32_t)f2bf(a.x) | ((uint32_t)f2bf(a.y) << 16);
    o.y = (uint32_t)f2bf(a.z) | ((uint32_t)f2bf(a.w) << 16);
    o.z = (uint32_t)f2bf(b.x) | ((uint32_t)f2bf(b.y) << 16);
    o.w = (uint32_t)f2bf(b.z) | ((uint32_t)f2bf(b.w) << 16);
    *(uint4*)(Xb + tid * 8) = o;
}

__global__ void scatter_kernel(const float* __restrict__ vals,
                               const int* __restrict__ rows,
                               const int* __restrict__ cols,
                               u16* __restrict__ Wb, int nnz) {
    int i = blockIdx.x * blockDim.x + threadIdx.x;
    if (i < nnz) {
        Wb[(size_t)rows[i] * IN_F + cols[i]] = f2bf(vals[i]);  // indices unique -> no atomics
    }
}

// ---------- GEMM: Y = Xb @ Wb^T + bias (both operands K-contiguous row-major) ----------
typedef __bf16 bf16x8 __attribute__((ext_vector_type(8)));
typedef float  f32x4  __attribute__((ext_vector_type(4)));

__device__ __forceinline__ void gld_lds16(const void* g, void* l) {
    __builtin_amdgcn_global_load_lds(
        (const __attribute__((address_space(1))) uint32_t*)(uintptr_t)g,
        (__attribute__((address_space(3))) uint32_t*)(uintptr_t)l,
        16, 0, 0);
}

__global__ __launch_bounds__(256)
void gemm_kernel(const u16* __restrict__ Xb, const u16* __restrict__ Wb,
                 const float* __restrict__ bias, float* __restrict__ out) {
    // 128x128 tile, BK=32, 4 waves each owning a 64x64 quadrant (4x4 frags of 16x16).
    __shared__ __align__(16) u16 ldsA[128 * 32];
    __shared__ __align__(16) u16 ldsB[128 * 32];

    const int tid  = threadIdx.x;
    const int lane = tid & 63;
    const int wid  = tid >> 6;
    const int wr   = wid >> 1;          // wave row quadrant (0..1)
    const int wc   = wid & 1;           // wave col quadrant (0..1)
    const int br   = blockIdx.y * 128;  // batch rows
    const int bc   = blockIdx.x * 128;  // out_f cols (= W rows)

    // staging geometry: 1KB chunk = 16 rows x 32 k; lane i -> row i/4, k (i&3)*8
    const int sr = lane >> 2;
    const int sk = (lane & 3) * 8;

    f32x4 acc[4][4] = {};

    for (int kt = 0; kt < IN_F; kt += 32) {
#pragma unroll
        for (int t = 0; t < 2; ++t) {
            const int c = wid * 2 + t;  // chunk 0..7
            gld_lds16(Xb + (size_t)(br + c * 16 + sr) * IN_F + kt + sk, &ldsA[c * 512]);
            gld_lds16(Wb + (size_t)(bc + c * 16 + sr) * IN_F + kt + sk, &ldsB[c * 512]);
        }
        __syncthreads();   // compiler drains vmcnt before s_barrier

        bf16x8 a[4], b[4];
#pragma unroll
        for (int m = 0; m < 4; ++m) {
            const int idx = (wr * 64 + m * 16 + (lane & 15)) * 32 + (lane >> 4) * 8;
            a[m] = __builtin_bit_cast(bf16x8, *(const uint4*)&ldsA[idx]);
        }
#pragma unroll
        for (int n = 0; n < 4; ++n) {
            const int idx = (wc * 64 + n * 16 + (lane & 15)) * 32 + (lane >> 4) * 8;
            b[n] = __builtin_bit_cast(bf16x8, *(const uint4*)&ldsB[idx]);
        }
#pragma unroll
        for (int m = 0; m < 4; ++m)
#pragma unroll
            for (int n = 0; n < 4; ++n)
                acc[m][n] = __builtin_amdgcn_mfma_f32_16x16x32_bf16(a[m], b[n], acc[m][n], 0, 0, 0);
        __syncthreads();
    }

    // epilogue: C/D layout col = lane&15, row = (lane>>4)*4 + j   [verified m89/m91]
    const int cl = lane & 15;
    const int rg = (lane >> 4) * 4;
#pragma unroll
    for (int n = 0; n < 4; ++n) {
        const int col = bc + wc * 64 + n * 16 + cl;
        const float bv = bias[col];
#pragma unroll
        for (int m = 0; m < 4; ++m) {
            const int row0 = br + wr * 64 + m * 16 + rg;
#pragma unroll
            for (int j = 0; j < 4; ++j) {
                out[(size_t)(row0 + j) * OUT_F + col] = acc[m][n][j] + bv;
            }
        }
    }
}

// ---------- launch ----------
extern "C" void kernel_launch(void* const* d_in, const int* in_sizes, int n_in,
                              void* d_out, int out_size, void* d_ws, size_t ws_size,
                              hipStream_t stream) {
    const float* X    = (const float*)d_in[0];
    const float* vals = (const float*)d_in[1];
    const int*   rows = (const int*)d_in[2];
    const int*   cols = (const int*)d_in[3];
    const float* bias = (const float*)d_in[4];
    float*       out  = (float*)d_out;
    const int    nnz  = in_sizes[1];

    u16* Wb = (u16*)d_ws;                                   // 32 MB bf16 W image
    u16* Xb = (u16*)((char*)d_ws + (size_t)OUT_F * IN_F * 2); // 32 MB bf16 X image

    // 16.7M elements, 8 per thread, 256 threads/block -> 8192 blocks
    zero_w_kernel<<<8192, 256, 0, stream>>>(Wb);
    convert_x_kernel<<<8192, 256, 0, stream>>>(X, Xb);
    scatter_kernel<<<(nnz + 255) / 256, 256, 0, stream>>>(vals, rows, cols, Wb, nnz);

    dim3 grid(OUT_F / 128, BATCH / 128);
    gemm_kernel<<<grid, 256, 0, stream>>>(Xb, Wb, bias, out);
}

// Round 2
// 147.539 us; speedup vs baseline: 1.4584x; 1.4584x over previous
//
#include <hip/hip_runtime.h>
#include <hip/hip_bf16.h>
#include <stdint.h>

typedef unsigned short u16;

#define IN_F  4096
#define OUT_F 4096
#define BATCH 4096

// ---------- bf16 helpers ----------
__device__ __forceinline__ u16 f2bf(float f) {
    uint32_t u = __float_as_uint(f);
    uint32_t r = u + 0x7FFFu + ((u >> 16) & 1u);   // round-to-nearest-even
    return (u16)(r >> 16);
}

// ---------- prep kernels ----------
__global__ void zero_w_kernel(u16* __restrict__ Wb) {
    size_t tid = (size_t)blockIdx.x * blockDim.x + threadIdx.x;
    uint4 z = {0u, 0u, 0u, 0u};
    *(uint4*)(Wb + tid * 8) = z;
}

__global__ void convert_x_kernel(const float* __restrict__ X, u16* __restrict__ Xb) {
    size_t tid = (size_t)blockIdx.x * blockDim.x + threadIdx.x;
    const float4* p = (const float4*)(X + tid * 8);
    float4 a = p[0];
    float4 b = p[1];
    uint4 o;
    o.x = (uint32_t)f2bf(a.x) | ((uint32_t)f2bf(a.y) << 16);
    o.y = (uint32_t)f2bf(a.z) | ((uint32_t)f2bf(a.w) << 16);
    o.z = (uint32_t)f2bf(b.x) | ((uint32_t)f2bf(b.y) << 16);
    o.w = (uint32_t)f2bf(b.z) | ((uint32_t)f2bf(b.w) << 16);
    *(uint4*)(Xb + tid * 8) = o;
}

__global__ void scatter_kernel(const float* __restrict__ vals,
                               const int* __restrict__ rows,
                               const int* __restrict__ cols,
                               u16* __restrict__ Wb, int nnz) {
    int i = blockIdx.x * blockDim.x + threadIdx.x;
    if (i < nnz) {
        Wb[(size_t)rows[i] * IN_F + cols[i]] = f2bf(vals[i]);  // unique indices
    }
}

// ---------- GEMM: Y = Xb @ Wb^T + bias ----------
// 256x256 tile, 512 threads (8 waves, 2Mx4N), per-wave 128x64 output.
// LDS: 4-slot ring of K-slices (BK=32): slot = A[256][32] + B[256][32] bf16 = 32 KB. 128 KB total.
// Phase g: vmcnt(8); barrier; stage khalf g+3 -> slot (g+3)&3; ds_read slot g&3; 32 MFMA.
typedef __bf16 bf16x8 __attribute__((ext_vector_type(8)));
typedef float  f32x4  __attribute__((ext_vector_type(4)));

#define NPH   (IN_F / 32)      // 128 K-phases
#define SLOTW 16384            // u16 per 32KB slot

__device__ __forceinline__ void gld_lds16(const void* g, void* l) {
    __builtin_amdgcn_global_load_lds(
        (const __attribute__((address_space(1))) uint32_t*)(uintptr_t)g,
        (__attribute__((address_space(3))) uint32_t*)(uintptr_t)l,
        16, 0, 0);
}

__global__ __launch_bounds__(512, 2)
void gemm_kernel(const u16* __restrict__ Xb, const u16* __restrict__ Wb,
                 const float* __restrict__ bias, float* __restrict__ out) {
    extern __shared__ __align__(16) u16 lds[];   // 4 * 16384 u16 = 128 KB

    const int tid  = threadIdx.x;
    const int lane = tid & 63;
    const int w    = tid >> 6;       // wave 0..7
    const int wr   = w >> 2;         // 0..1 (M)
    const int wc   = w & 3;          // 0..3 (N)

    // XCD-aware bijective swizzle (256 blocks, 256%8==0)
    const int bid = blockIdx.x;
    const int swz = (bid & 7) * 32 + (bid >> 3);
    const int br  = (swz >> 4) * 256;    // batch rows
    const int bc  = (swz & 15) * 256;    // out cols (= W rows)

    // ---- staging geometry (write side) ----
    // chunk c (1KB) = 16 rows x 32 k of one matrix; lane l -> row l>>2, k-slot l&3.
    // Inverse-swizzled GLOBAL source so that LDS[row][s] holds global k-slot s^((row>>1)&3).
    const int l2 = lane >> 2;                          // row within chunk
    const int sw = (lane & 3) ^ ((lane >> 3) & 3);     // swizzled global k-slot
    const u16* asrc[4];   // base (khalf 0) per this wave's 4 chunks
    int        adst[4];   // u16 offset within a slot
#pragma unroll
    for (int i = 0; i < 4; ++i) {
        const int c = w * 4 + i;     // 0..31; <16 -> A, else B
        if (c < 16) {
            asrc[i] = Xb + (size_t)(br + c * 16 + l2) * IN_F + sw * 8;
            adst[i] = c * 512;
        } else {
            asrc[i] = Wb + (size_t)(bc + (c - 16) * 16 + l2) * IN_F + sw * 8;
            adst[i] = 8192 + (c - 16) * 512;
        }
    }

    // ---- fragment read offsets (read side, swizzled) ----
    const int sp = (lane >> 4) ^ ((lane >> 1) & 3);    // swizzled 16B slot within 64B row
    int aoff[8], boff[4];
#pragma unroll
    for (int m = 0; m < 8; ++m)
        aoff[m] = (wr * 128 + m * 16 + (lane & 15)) * 32 + sp * 8;
#pragma unroll
    for (int n = 0; n < 4; ++n)
        boff[n] = 8192 + (wc * 64 + n * 16 + (lane & 15)) * 32 + sp * 8;

    f32x4 acc[8][4] = {};

    // ---- prologue: stage khalfs 0,1,2 into slots 0,1,2 (12 loads/wave outstanding) ----
#pragma unroll
    for (int kh = 0; kh < 3; ++kh) {
        const int sbase = (kh & 3) * SLOTW;
#pragma unroll
        for (int i = 0; i < 4; ++i)
            gld_lds16(asrc[i] + kh * 32, lds + sbase + adst[i]);
    }

    // ---- phase body ----
#define PHASE(G, VMLIT, STG)                                                    \
    do {                                                                        \
        asm volatile("s_waitcnt vmcnt(" #VMLIT ")" ::: "memory");               \
        __builtin_amdgcn_s_barrier();                                           \
        if (STG) {                                                              \
            const int kh = (G) + 3;                                             \
            const int sbase = (kh & 3) * SLOTW;                                 \
            _Pragma("unroll")                                                   \
            for (int i = 0; i < 4; ++i)                                         \
                gld_lds16(asrc[i] + (size_t)kh * 32, lds + sbase + adst[i]);    \
        }                                                                       \
        const u16* sl = lds + ((G) & 3) * SLOTW;                                \
        bf16x8 a[8], b[4];                                                      \
        _Pragma("unroll")                                                       \
        for (int m = 0; m < 8; ++m)                                             \
            a[m] = __builtin_bit_cast(bf16x8, *(const uint4*)(sl + aoff[m]));   \
        _Pragma("unroll")                                                       \
        for (int n = 0; n < 4; ++n)                                             \
            b[n] = __builtin_bit_cast(bf16x8, *(const uint4*)(sl + boff[n]));   \
        __builtin_amdgcn_s_setprio(1);                                          \
        _Pragma("unroll")                                                       \
        for (int m = 0; m < 8; ++m)                                             \
            _Pragma("unroll")                                                   \
            for (int n = 0; n < 4; ++n)                                         \
                acc[m][n] = __builtin_amdgcn_mfma_f32_16x16x32_bf16(            \
                    a[m], b[n], acc[m][n], 0, 0, 0);                            \
        __builtin_amdgcn_s_setprio(0);                                          \
    } while (0)

    // main loop: stage khalf g+3 while computing g; counted vmcnt (never 0)
    for (int g = 0; g < NPH - 3; ++g)
        PHASE(g, 8, true);
    // epilogue phases: drain 8 -> 4 -> 0
    PHASE(NPH - 3, 8, false);
    PHASE(NPH - 2, 4, false);
    PHASE(NPH - 1, 0, false);
#undef PHASE

    // ---- C write: col = lane&15, row = (lane>>4)*4 + j  [verified layout] ----
    const int cl = lane & 15;
    const int rg = (lane >> 4) * 4;
#pragma unroll
    for (int n = 0; n < 4; ++n) {
        const int col = bc + wc * 64 + n * 16 + cl;
        const float bv = bias[col];
#pragma unroll
        for (int m = 0; m < 8; ++m) {
            const int row0 = br + wr * 128 + m * 16 + rg;
#pragma unroll
            for (int j = 0; j < 4; ++j)
                out[(size_t)(row0 + j) * OUT_F + col] = acc[m][n][j] + bv;
        }
    }
}

// ---------- launch ----------
extern "C" void kernel_launch(void* const* d_in, const int* in_sizes, int n_in,
                              void* d_out, int out_size, void* d_ws, size_t ws_size,
                              hipStream_t stream) {
    const float* X    = (const float*)d_in[0];
    const float* vals = (const float*)d_in[1];
    const int*   rows = (const int*)d_in[2];
    const int*   cols = (const int*)d_in[3];
    const float* bias = (const float*)d_in[4];
    float*       out  = (float*)d_out;
    const int    nnz  = in_sizes[1];

    u16* Wb = (u16*)d_ws;
    u16* Xb = (u16*)((char*)d_ws + (size_t)OUT_F * IN_F * 2);

    zero_w_kernel<<<8192, 256, 0, stream>>>(Wb);
    convert_x_kernel<<<8192, 256, 0, stream>>>(X, Xb);
    scatter_kernel<<<(nnz + 255) / 256, 256, 0, stream>>>(vals, rows, cols, Wb, nnz);

    static bool attr_set = false;  // deterministic: same effect every call
    (void)hipFuncSetAttribute((const void*)gemm_kernel,
                              hipFuncAttributeMaxDynamicSharedMemorySize, 131072);
    (void)attr_set;

    gemm_kernel<<<dim3(256), dim3(512), 131072, stream>>>(Xb, Wb, bias, out);
}

// Round 3
// 141.387 us; speedup vs baseline: 1.5219x; 1.0435x over previous
//
#include <hip/hip_runtime.h>
#include <hip/hip_bf16.h>
#include <stdint.h>

typedef unsigned short u16;

#define IN_F  4096
#define OUT_F 4096
#define BATCH 4096

// ---------- bf16 helpers ----------
__device__ __forceinline__ u16 f2bf(float f) {
    uint32_t u = __float_as_uint(f);
    uint32_t r = u + 0x7FFFu + ((u >> 16) & 1u);   // round-to-nearest-even
    return (u16)(r >> 16);
}

// ---------- prep kernels ----------
// blocks [0,8192): zero Wb; blocks [8192,16384): convert X -> Xb. One launch.
__global__ void prep_kernel(const float* __restrict__ X, u16* __restrict__ Xb,
                            u16* __restrict__ Wb) {
    if (blockIdx.x < 8192) {
        size_t tid = (size_t)blockIdx.x * blockDim.x + threadIdx.x;
        uint4 z = {0u, 0u, 0u, 0u};
        *(uint4*)(Wb + tid * 8) = z;
    } else {
        size_t tid = (size_t)(blockIdx.x - 8192) * blockDim.x + threadIdx.x;
        const float4* p = (const float4*)(X + tid * 8);
        float4 a = p[0];
        float4 b = p[1];
        uint4 o;
        o.x = (uint32_t)f2bf(a.x) | ((uint32_t)f2bf(a.y) << 16);
        o.y = (uint32_t)f2bf(a.z) | ((uint32_t)f2bf(a.w) << 16);
        o.z = (uint32_t)f2bf(b.x) | ((uint32_t)f2bf(b.y) << 16);
        o.w = (uint32_t)f2bf(b.z) | ((uint32_t)f2bf(b.w) << 16);
        *(uint4*)(Xb + tid * 8) = o;
    }
}

__global__ void scatter_kernel(const float* __restrict__ vals,
                               const int* __restrict__ rows,
                               const int* __restrict__ cols,
                               u16* __restrict__ Wb, int nnz) {
    int i = blockIdx.x * blockDim.x + threadIdx.x;
    if (i < nnz) {
        Wb[(size_t)rows[i] * IN_F + cols[i]] = f2bf(vals[i]);  // unique indices
    }
}

// ---------- GEMM: Y = Xb @ Wb^T + bias ----------
// 256x256 tile, 512 threads (8 waves, 2Mx4N), per-wave 128x64 output.
// LDS: 4-slot ring of K-slices (BK=32); slot = A[256][32] + B[256][32] bf16 = 32 KB.
// Slice g, two template-shaped sub-phases (T3 fine interleave + T5):
//   vmcnt(8); BAR; read a0-3,b0-3; stage 2 gld; BAR; 16 MFMA;
//             read a4-7;           stage 2 gld; BAR; 16 MFMA
typedef __bf16 bf16x8 __attribute__((ext_vector_type(8)));
typedef float  f32x4  __attribute__((ext_vector_type(4)));

#define NPH   (IN_F / 32)      // 128 K-slices
#define SLOTW 16384            // u16 per 32KB slot

__device__ __forceinline__ void gld_lds16(const void* g, void* l) {
    __builtin_amdgcn_global_load_lds(
        (const __attribute__((address_space(1))) uint32_t*)(uintptr_t)g,
        (__attribute__((address_space(3))) uint32_t*)(uintptr_t)l,
        16, 0, 0);
}

__global__ __launch_bounds__(512, 2)
void gemm_kernel(const u16* __restrict__ Xb, const u16* __restrict__ Wb,
                 const float* __restrict__ bias, float* __restrict__ out) {
    extern __shared__ __align__(16) u16 lds[];   // 4 * 16384 u16 = 128 KB

    const int tid  = threadIdx.x;
    const int lane = tid & 63;
    const int w    = tid >> 6;       // wave 0..7
    const int wr   = w >> 2;         // 0..1 (M)
    const int wc   = w & 3;          // 0..3 (N)

    // XCD-aware bijective swizzle (256 blocks, 256%8==0)
    const int bid = blockIdx.x;
    const int swz = (bid & 7) * 32 + (bid >> 3);
    const int br  = (swz >> 4) * 256;    // batch rows
    const int bc  = (swz & 15) * 256;    // out cols (= W rows)

    // ---- staging geometry (write side) ----
    // chunk c (1KB) = 16 rows x 32 k; lane l -> row l>>2, k-slot l&3.
    // Inverse-swizzled GLOBAL source so LDS[row][s] holds global k-slot s^((row>>1)&3).
    const int l2 = lane >> 2;
    const int sw = (lane & 3) ^ ((lane >> 3) & 3);
    const u16* asrc[4];
    int        adst[4];
#pragma unroll
    for (int i = 0; i < 4; ++i) {
        const int c = w * 4 + i;     // 0..31; <16 -> A, else B
        if (c < 16) {
            asrc[i] = Xb + (size_t)(br + c * 16 + l2) * IN_F + sw * 8;
            adst[i] = c * 512;
        } else {
            asrc[i] = Wb + (size_t)(bc + (c - 16) * 16 + l2) * IN_F + sw * 8;
            adst[i] = 8192 + (c - 16) * 512;
        }
    }

    // ---- fragment read offsets (read side, swizzled; 0-conflict verified) ----
    const int sp = (lane >> 4) ^ ((lane >> 1) & 3);
    int aoff[8], boff[4];
#pragma unroll
    for (int m = 0; m < 8; ++m)
        aoff[m] = (wr * 128 + m * 16 + (lane & 15)) * 32 + sp * 8;
#pragma unroll
    for (int n = 0; n < 4; ++n)
        boff[n] = 8192 + (wc * 64 + n * 16 + (lane & 15)) * 32 + sp * 8;

    f32x4 acc[8][4] = {};

    // ---- prologue: stage slices 0,1,2 into slots 0,1,2 ----
#pragma unroll
    for (int kh = 0; kh < 3; ++kh) {
        const int sbase = (kh & 3) * SLOTW;
#pragma unroll
        for (int i = 0; i < 4; ++i)
            gld_lds16(asrc[i] + kh * 32, lds + sbase + adst[i]);
    }

    // ---- slice body: two sub-phases ----
#define SLICE(G, VMLIT, STG)                                                    \
    do {                                                                        \
        asm volatile("s_waitcnt vmcnt(" #VMLIT ")" ::: "memory");               \
        __builtin_amdgcn_s_barrier();                                           \
        const u16* sl = lds + ((G) & 3) * SLOTW;                                \
        const int  sb = (((G) + 3) & 3) * SLOTW;                                \
        bf16x8 a[4], b[4];                                                      \
        _Pragma("unroll")                                                       \
        for (int m = 0; m < 4; ++m)                                             \
            a[m] = __builtin_bit_cast(bf16x8, *(const uint4*)(sl + aoff[m]));   \
        _Pragma("unroll")                                                       \
        for (int n = 0; n < 4; ++n)                                             \
            b[n] = __builtin_bit_cast(bf16x8, *(const uint4*)(sl + boff[n]));   \
        if (STG) {                                                              \
            gld_lds16(asrc[0] + (size_t)((G) + 3) * 32, lds + sb + adst[0]);    \
            gld_lds16(asrc[1] + (size_t)((G) + 3) * 32, lds + sb + adst[1]);    \
        }                                                                       \
        __builtin_amdgcn_s_barrier();                                           \
        __builtin_amdgcn_s_setprio(1);                                          \
        _Pragma("unroll")                                                       \
        for (int m = 0; m < 4; ++m)                                             \
            _Pragma("unroll")                                                   \
            for (int n = 0; n < 4; ++n)                                         \
                acc[m][n] = __builtin_amdgcn_mfma_f32_16x16x32_bf16(            \
                    a[m], b[n], acc[m][n], 0, 0, 0);                            \
        __builtin_amdgcn_s_setprio(0);                                          \
        _Pragma("unroll")                                                       \
        for (int m = 0; m < 4; ++m)                                             \
            a[m] = __builtin_bit_cast(bf16x8, *(const uint4*)(sl + aoff[m+4])); \
        if (STG) {                                                              \
            gld_lds16(asrc[2] + (size_t)((G) + 3) * 32, lds + sb + adst[2]);    \
            gld_lds16(asrc[3] + (size_t)((G) + 3) * 32, lds + sb + adst[3]);    \
        }                                                                       \
        __builtin_amdgcn_s_barrier();                                           \
        __builtin_amdgcn_s_setprio(1);                                          \
        _Pragma("unroll")                                                       \
        for (int m = 0; m < 4; ++m)                                             \
            _Pragma("unroll")                                                   \
            for (int n = 0; n < 4; ++n)                                         \
                acc[m + 4][n] = __builtin_amdgcn_mfma_f32_16x16x32_bf16(        \
                    a[m], b[n], acc[m + 4][n], 0, 0, 0);                        \
        __builtin_amdgcn_s_setprio(0);                                          \
    } while (0)

    for (int g = 0; g < NPH - 3; ++g)
        SLICE(g, 8, true);
    SLICE(NPH - 3, 8, false);
    SLICE(NPH - 2, 4, false);
    SLICE(NPH - 1, 0, false);
#undef SLICE

    // ---- C write: col = lane&15, row = (lane>>4)*4 + j ----
    const int cl = lane & 15;
    const int rg = (lane >> 4) * 4;
#pragma unroll
    for (int n = 0; n < 4; ++n) {
        const int col = bc + wc * 64 + n * 16 + cl;
        const float bv = bias[col];
#pragma unroll
        for (int m = 0; m < 8; ++m) {
            const int row0 = br + wr * 128 + m * 16 + rg;
#pragma unroll
            for (int j = 0; j < 4; ++j)
                out[(size_t)(row0 + j) * OUT_F + col] = acc[m][n][j] + bv;
        }
    }
}

// ---------- launch ----------
extern "C" void kernel_launch(void* const* d_in, const int* in_sizes, int n_in,
                              void* d_out, int out_size, void* d_ws, size_t ws_size,
                              hipStream_t stream) {
    const float* X    = (const float*)d_in[0];
    const float* vals = (const float*)d_in[1];
    const int*   rows = (const int*)d_in[2];
    const int*   cols = (const int*)d_in[3];
    const float* bias = (const float*)d_in[4];
    float*       out  = (float*)d_out;
    const int    nnz  = in_sizes[1];

    u16* Wb = (u16*)d_ws;
    u16* Xb = (u16*)((char*)d_ws + (size_t)OUT_F * IN_F * 2);

    prep_kernel<<<16384, 256, 0, stream>>>(X, Xb, Wb);
    scatter_kernel<<<(nnz + 255) / 256, 256, 0, stream>>>(vals, rows, cols, Wb, nnz);

    (void)hipFuncSetAttribute((const void*)gemm_kernel,
                              hipFuncAttributeMaxDynamicSharedMemorySize, 131072);

    gemm_kernel<<<dim3(256), dim3(512), 131072, stream>>>(Xb, Wb, bias, out);
}